// Round 3
// baseline (174.038 us; speedup 1.0000x reference)
//
#include <hip/hip_runtime.h>
#include <stdint.h>

#define NB   8
#define NN   2048
#define FIN  128
#define FOUT 64
#define NEGINF (-9e15f)
#define MAXS 512

__device__ __forceinline__ uint32_t rotl32(uint32_t x, uint32_t r) {
  return (x << r) | (x >> (32u - r));
}

// JAX threefry2x32 with key = (0, 42)
__device__ __forceinline__ void threefry_0_42(uint32_t x0, uint32_t x1,
                                              uint32_t& o0, uint32_t& o1) {
  const uint32_t k0 = 0u, k1 = 42u;
  const uint32_t k2 = 0x1BD11BDAu ^ k0 ^ k1;
  x0 += k0; x1 += k1;
#define TFR(r) { x0 += x1; x1 = rotl32(x1, r); x1 ^= x0; }
  TFR(13u) TFR(15u) TFR(26u) TFR(6u)   x0 += k1; x1 += k2 + 1u;
  TFR(17u) TFR(29u) TFR(16u) TFR(24u)  x0 += k2; x1 += k0 + 2u;
  TFR(13u) TFR(15u) TFR(26u) TFR(6u)   x0 += k0; x1 += k1 + 3u;
  TFR(17u) TFR(29u) TFR(16u) TFR(24u)  x0 += k1; x1 += k2 + 4u;
  TFR(13u) TFR(15u) TFR(26u) TFR(6u)   x0 += k2; x1 += k0 + 5u;
#undef TFR
  o0 = x0; o1 = x1;
}

// Partitionable threefry: bits = o0^o1 of threefry(key, 0, v); keep iff bit31==0.
__device__ __forceinline__ bool keep_bit(uint32_t v) {
  uint32_t o0, o1;
  threefry_0_42(0u, v, o0, o1);
  return !((o0 ^ o1) >> 31);
}

// Kernel A: Wh = h @ W, Wh1 = Wh@a[:64], Wh2 = Wh@a[64:]
// 32 rows/block, 8 rows/wave: each wLds read amortized over 8 accumulators.
__global__ __launch_bounds__(256) void wh_kernel(
    const float* __restrict__ h, const float* __restrict__ W,
    const float* __restrict__ a, float* __restrict__ Wh,
    float* __restrict__ Wh1, float* __restrict__ Wh2) {
  __shared__ __align__(16) float wLds[FIN * FOUT];   // 32 KB
  __shared__ __align__(16) float hLds[32][FIN];      // 16 KB
  const int t = threadIdx.x;
  const int wv = t >> 6, lane = t & 63;
  const int rbase = blockIdx.x * 32;
  {
    const float4* W4 = reinterpret_cast<const float4*>(W);
    float4* wL4 = reinterpret_cast<float4*>(wLds);
#pragma unroll
    for (int idx = t; idx < FIN * FOUT / 4; idx += 256) wL4[idx] = W4[idx];
    const float4* h4 = reinterpret_cast<const float4*>(h + (size_t)rbase * FIN);
    float4* hL4 = reinterpret_cast<float4*>(&hLds[0][0]);
#pragma unroll
    for (int idx = t; idx < 32 * FIN / 4; idx += 256) hL4[idx] = h4[idx];
  }
  __syncthreads();
  const int r0 = wv * 8;
  float acc[8] = {0.f, 0.f, 0.f, 0.f, 0.f, 0.f, 0.f, 0.f};
  for (int k4 = 0; k4 < FIN; k4 += 4) {
    float4 hb[8];
#pragma unroll
    for (int r = 0; r < 8; ++r)
      hb[r] = *reinterpret_cast<const float4*>(&hLds[r0 + r][k4]);  // broadcast
#pragma unroll
    for (int e = 0; e < 4; ++e) {
      const float w = wLds[(k4 + e) * FOUT + lane];  // bank = lane&31, 2-way free
#pragma unroll
      for (int r = 0; r < 8; ++r) {
        const float hv = (e == 0) ? hb[r].x : (e == 1) ? hb[r].y
                        : (e == 2) ? hb[r].z : hb[r].w;
        acc[r] += hv * w;
      }
    }
  }
  const float a1 = a[lane], a2 = a[FOUT + lane];
#pragma unroll
  for (int r = 0; r < 8; ++r) {
    const int row = rbase + r0 + r;
    Wh[(size_t)row * FOUT + lane] = acc[r];
    float x1 = acc[r] * a1, x2 = acc[r] * a2;
#pragma unroll
    for (int off = 32; off >= 1; off >>= 1) {
      x1 += __shfl_xor(x1, off);
      x2 += __shfl_xor(x2, off);
    }
    if (lane == 0) { Wh1[row] = x1; Wh2[row] = x2; }
  }
}

// Kernel B: per block: batch pair (b, b+4), row i.
// phase 1: e -> registers, row max m (fmax only, no exp).
// phase 2: p = exp(e-m), sum s; survivors (p>1e-10) compacted into LDS.
// phase 3: threefry ONLY on compacted survivors (~2-5 per row).
// phase 4: sparse PV over survivor list.
__global__ __launch_bounds__(256) void attn_kernel(
    const int* __restrict__ adj, const float* __restrict__ Wh,
    const float* __restrict__ Wh1, const float* __restrict__ Wh2,
    float* __restrict__ out) {
  __shared__ float mredA[2][4], sredA[2][4];
  __shared__ int cnt[2];
  __shared__ int   survJ[2][MAXS];   // 4 KB
  __shared__ float survP[2][MAXS];   // 4 KB
  __shared__ float accL[2][4][FOUT]; // 2 KB

  const int i = blockIdx.x & (NN - 1);
  const int b = blockIdx.x >> 11;                 // 0..3
  const int b2 = b + 4;
  const int t = threadIdx.x;
  const int wv = t >> 6, lane = t & 63;

  const float wh1_0 = Wh1[b * NN + i];
  const float wh1_1 = Wh1[b2 * NN + i];
  const size_t adjBase0 = ((size_t)(b * NN) + i) * NN;
  const size_t adjBase1 = ((size_t)(b2 * NN) + i) * NN;

  float e0[8], e1[8];
  float m0 = -3.0e38f, m1 = -3.0e38f;
#pragma unroll
  for (int it = 0; it < 2; ++it) {
    const int j = it * 1024 + t * 4;
    const int4   av0 = *reinterpret_cast<const int4*>(adj + adjBase0 + j);
    const int4   av1 = *reinterpret_cast<const int4*>(adj + adjBase1 + j);
    const float4 w0 = *reinterpret_cast<const float4*>(Wh2 + (size_t)b * NN + j);
    const float4 w1 = *reinterpret_cast<const float4*>(Wh2 + (size_t)b2 * NN + j);
    const int aa0[4] = {av0.x, av0.y, av0.z, av0.w};
    const int aa1[4] = {av1.x, av1.y, av1.z, av1.w};
    const float ww0[4] = {w0.x, w0.y, w0.z, w0.w};
    const float ww1[4] = {w1.x, w1.y, w1.z, w1.w};
#pragma unroll
    for (int e = 0; e < 4; ++e) {
      float x = wh1_0 + ww0[e];
      x = (x < 0.f) ? 0.2f * x : x;
      x = (aa0[e] > 0) ? x : NEGINF;
      e0[it * 4 + e] = x;
      m0 = fmaxf(m0, x);
      float y = wh1_1 + ww1[e];
      y = (y < 0.f) ? 0.2f * y : y;
      y = (aa1[e] > 0) ? y : NEGINF;
      e1[it * 4 + e] = y;
      m1 = fmaxf(m1, y);
    }
  }
#pragma unroll
  for (int off = 1; off < 64; off <<= 1) {
    m0 = fmaxf(m0, __shfl_xor(m0, off));
    m1 = fmaxf(m1, __shfl_xor(m1, off));
  }
  if (lane == 0) { mredA[0][wv] = m0; mredA[1][wv] = m1; }
  if (t < 2) cnt[t] = 0;
  __syncthreads();
  m0 = fmaxf(fmaxf(mredA[0][0], mredA[0][1]), fmaxf(mredA[0][2], mredA[0][3]));
  m1 = fmaxf(fmaxf(mredA[1][0], mredA[1][1]), fmaxf(mredA[1][2], mredA[1][3]));

  float s0 = 0.f, s1 = 0.f;
#pragma unroll
  for (int k = 0; k < 8; ++k) {
    const int j = (k >> 2) * 1024 + t * 4 + (k & 3);
    float p = __expf(e0[k] - m0);
    s0 += p;
    if (p > 1e-10f) {
      const int idx = atomicAdd(&cnt[0], 1);
      if (idx < MAXS) { survJ[0][idx] = j; survP[0][idx] = p; }
    }
    p = __expf(e1[k] - m1);
    s1 += p;
    if (p > 1e-10f) {
      const int idx = atomicAdd(&cnt[1], 1);
      if (idx < MAXS) { survJ[1][idx] = j; survP[1][idx] = p; }
    }
  }
#pragma unroll
  for (int off = 1; off < 64; off <<= 1) {
    s0 += __shfl_xor(s0, off);
    s1 += __shfl_xor(s1, off);
  }
  if (lane == 0) { sredA[0][wv] = s0; sredA[1][wv] = s1; }
  __syncthreads();
  s0 = sredA[0][0] + sredA[0][1] + sredA[0][2] + sredA[0][3];
  s1 = sredA[1][0] + sredA[1][1] + sredA[1][2] + sredA[1][3];
  const float inv0 = 2.0f / s0;   // dropout 1/(1-p)=2 folded in
  const float inv1 = 2.0f / s1;
  const int c0 = min(cnt[0], MAXS), c1 = min(cnt[1], MAXS);

  // phase 3: lazy dropout, only on survivors
  for (int idx = t; idx < c0; idx += 256) {
    const uint32_t v = ((uint32_t)b << 22) | ((uint32_t)i << 11) | (uint32_t)survJ[0][idx];
    survP[0][idx] = keep_bit(v) ? survP[0][idx] * inv0 : 0.f;
  }
  for (int idx = t; idx < c1; idx += 256) {
    const uint32_t v = ((uint32_t)b2 << 22) | ((uint32_t)i << 11) | (uint32_t)survJ[1][idx];
    survP[1][idx] = keep_bit(v) ? survP[1][idx] * inv1 : 0.f;
  }
  __syncthreads();

  // phase 4: sparse PV over survivor list
  float acc0 = 0.f, acc1 = 0.f;
  for (int idx = wv; idx < c0; idx += 4) {
    const float c = survP[0][idx];
    if (c != 0.f)
      acc0 += c * Wh[((size_t)(b * NN + survJ[0][idx])) * FOUT + lane];
  }
  for (int idx = wv; idx < c1; idx += 4) {
    const float c = survP[1][idx];
    if (c != 0.f)
      acc1 += c * Wh[((size_t)(b2 * NN + survJ[1][idx])) * FOUT + lane];
  }
  accL[0][wv][lane] = acc0;
  accL[1][wv][lane] = acc1;
  __syncthreads();
  if (t < 128) {
    const int bb = t >> 6, f = t & 63;
    const float r = accL[bb][0][f] + accL[bb][1][f] + accL[bb][2][f] + accL[bb][3][f];
    const int bo = (bb == 0) ? b : b2;
    out[((size_t)bo * NN + i) * FOUT + f] = r;
  }
}

extern "C" void kernel_launch(void* const* d_in, const int* in_sizes, int n_in,
                              void* d_out, int out_size, void* d_ws, size_t ws_size,
                              hipStream_t stream) {
  const float* h   = (const float*)d_in[0];
  const int*   adj = (const int*)d_in[1];
  const float* W   = (const float*)d_in[2];
  const float* a   = (const float*)d_in[3];
  float* out = (float*)d_out;
  float* ws  = (float*)d_ws;

  float* Wh  = ws;                                 // 16384*64 floats
  float* Wh1 = ws + (size_t)NB * NN * FOUT;        // 16384
  float* Wh2 = Wh1 + NB * NN;                      // 16384

  wh_kernel<<<dim3((NB * NN) / 32), dim3(256), 0, stream>>>(h, W, a, Wh, Wh1, Wh2);
  attn_kernel<<<dim3((NB / 2) * NN), dim3(256), 0, stream>>>(adj, Wh, Wh1, Wh2, out);
}

// Round 4
// 57.266 us; speedup vs baseline: 3.0391x; 3.0391x over previous
//
#include <hip/hip_runtime.h>
#include <stdint.h>

#define NB   8
#define NN   2048
#define FIN  128
#define FOUT 64
#define NEGINF (-9e15f)
#define MAXS 512

__device__ __forceinline__ uint32_t rotl32(uint32_t x, uint32_t r) {
  return (x << r) | (x >> (32u - r));
}

// JAX threefry2x32 with key = (0, 42)
__device__ __forceinline__ void threefry_0_42(uint32_t x0, uint32_t x1,
                                              uint32_t& o0, uint32_t& o1) {
  const uint32_t k0 = 0u, k1 = 42u;
  const uint32_t k2 = 0x1BD11BDAu ^ k0 ^ k1;
  x0 += k0; x1 += k1;
#define TFR(r) { x0 += x1; x1 = rotl32(x1, r); x1 ^= x0; }
  TFR(13u) TFR(15u) TFR(26u) TFR(6u)   x0 += k1; x1 += k2 + 1u;
  TFR(17u) TFR(29u) TFR(16u) TFR(24u)  x0 += k2; x1 += k0 + 2u;
  TFR(13u) TFR(15u) TFR(26u) TFR(6u)   x0 += k0; x1 += k1 + 3u;
  TFR(17u) TFR(29u) TFR(16u) TFR(24u)  x0 += k1; x1 += k2 + 4u;
  TFR(13u) TFR(15u) TFR(26u) TFR(6u)   x0 += k2; x1 += k0 + 5u;
#undef TFR
  o0 = x0; o1 = x1;
}

// Partitionable threefry: bits = o0^o1 of threefry(key, 0, v); keep iff bit31==0.
__device__ __forceinline__ bool keep_bit(uint32_t v) {
  uint32_t o0, o1;
  threefry_0_42(0u, v, o0, o1);
  return !((o0 ^ o1) >> 31);
}

// Kernel A (round-2 shape: 1 row/wave, scalar acc — no spill risk):
// Wh = h @ W, Wh1 = Wh@a[:64], Wh2 = Wh@a[64:]
__global__ __launch_bounds__(256) void wh_kernel(
    const float* __restrict__ h, const float* __restrict__ W,
    const float* __restrict__ a, float* __restrict__ Wh,
    float* __restrict__ Wh1, float* __restrict__ Wh2) {
  __shared__ __align__(16) float wLds[FIN * FOUT];   // 32 KB
  __shared__ __align__(16) float hLds[4][FIN];       // 2 KB
  const int t = threadIdx.x;
  const int wv = t >> 6, lane = t & 63;
  {
    const float4* W4 = reinterpret_cast<const float4*>(W);
    float4* wL4 = reinterpret_cast<float4*>(wLds);
    for (int idx = t; idx < FIN * FOUT / 4; idx += 256) wL4[idx] = W4[idx];
  }
  const int row = blockIdx.x * 4 + wv;           // [0, 16384)
  {
    float2 v = *reinterpret_cast<const float2*>(&h[(size_t)row * FIN + lane * 2]);
    hLds[wv][lane * 2]     = v.x;
    hLds[wv][lane * 2 + 1] = v.y;
  }
  __syncthreads();
  float acc = 0.f;
#pragma unroll 8
  for (int k = 0; k < FIN; ++k) acc += hLds[wv][k] * wLds[k * FOUT + lane];
  Wh[(size_t)row * FOUT + lane] = acc;
  float x1 = acc * a[lane];
  float x2 = acc * a[FOUT + lane];
#pragma unroll
  for (int off = 32; off >= 1; off >>= 1) {
    x1 += __shfl_xor(x1, off);
    x2 += __shfl_xor(x2, off);
  }
  if (lane == 0) { Wh1[row] = x1; Wh2[row] = x2; }
}

// Kernel B: per block: batch pair (b, b+4), row i.
// phase 1: e -> registers, row max m (fmax only, no exp).
// phase 2: p = exp(e-m), sum s; survivors (p>1e-10) compacted into LDS.
// phase 3: threefry ONLY on compacted survivors (~2-5 per row).
// phase 4: sparse PV over survivor list.
__global__ __launch_bounds__(256) void attn_kernel(
    const int* __restrict__ adj, const float* __restrict__ Wh,
    const float* __restrict__ Wh1, const float* __restrict__ Wh2,
    float* __restrict__ out) {
  __shared__ float mredA[2][4], sredA[2][4];
  __shared__ int cnt[2];
  __shared__ int   survJ[2][MAXS];   // 4 KB
  __shared__ float survP[2][MAXS];   // 4 KB
  __shared__ float accL[2][4][FOUT]; // 2 KB

  const int i = blockIdx.x & (NN - 1);
  const int b = blockIdx.x >> 11;                 // 0..3
  const int b2 = b + 4;
  const int t = threadIdx.x;
  const int wv = t >> 6, lane = t & 63;

  const float wh1_0 = Wh1[b * NN + i];
  const float wh1_1 = Wh1[b2 * NN + i];
  const size_t adjBase0 = ((size_t)(b * NN) + i) * NN;
  const size_t adjBase1 = ((size_t)(b2 * NN) + i) * NN;

  float e0[8], e1[8];
  float m0 = -3.0e38f, m1 = -3.0e38f;
#pragma unroll
  for (int it = 0; it < 2; ++it) {
    const int j = it * 1024 + t * 4;
    const int4   av0 = *reinterpret_cast<const int4*>(adj + adjBase0 + j);
    const int4   av1 = *reinterpret_cast<const int4*>(adj + adjBase1 + j);
    const float4 w0 = *reinterpret_cast<const float4*>(Wh2 + (size_t)b * NN + j);
    const float4 w1 = *reinterpret_cast<const float4*>(Wh2 + (size_t)b2 * NN + j);
    const int aa0[4] = {av0.x, av0.y, av0.z, av0.w};
    const int aa1[4] = {av1.x, av1.y, av1.z, av1.w};
    const float ww0[4] = {w0.x, w0.y, w0.z, w0.w};
    const float ww1[4] = {w1.x, w1.y, w1.z, w1.w};
#pragma unroll
    for (int e = 0; e < 4; ++e) {
      float x = wh1_0 + ww0[e];
      x = (x < 0.f) ? 0.2f * x : x;
      x = (aa0[e] > 0) ? x : NEGINF;
      e0[it * 4 + e] = x;
      m0 = fmaxf(m0, x);
      float y = wh1_1 + ww1[e];
      y = (y < 0.f) ? 0.2f * y : y;
      y = (aa1[e] > 0) ? y : NEGINF;
      e1[it * 4 + e] = y;
      m1 = fmaxf(m1, y);
    }
  }
#pragma unroll
  for (int off = 1; off < 64; off <<= 1) {
    m0 = fmaxf(m0, __shfl_xor(m0, off));
    m1 = fmaxf(m1, __shfl_xor(m1, off));
  }
  if (lane == 0) { mredA[0][wv] = m0; mredA[1][wv] = m1; }
  if (t < 2) cnt[t] = 0;
  __syncthreads();
  m0 = fmaxf(fmaxf(mredA[0][0], mredA[0][1]), fmaxf(mredA[0][2], mredA[0][3]));
  m1 = fmaxf(fmaxf(mredA[1][0], mredA[1][1]), fmaxf(mredA[1][2], mredA[1][3]));

  float s0 = 0.f, s1 = 0.f;
#pragma unroll
  for (int k = 0; k < 8; ++k) {
    const int j = (k >> 2) * 1024 + t * 4 + (k & 3);
    float p = __expf(e0[k] - m0);
    s0 += p;
    if (p > 1e-10f) {
      const int idx = atomicAdd(&cnt[0], 1);
      if (idx < MAXS) { survJ[0][idx] = j; survP[0][idx] = p; }
    }
    p = __expf(e1[k] - m1);
    s1 += p;
    if (p > 1e-10f) {
      const int idx = atomicAdd(&cnt[1], 1);
      if (idx < MAXS) { survJ[1][idx] = j; survP[1][idx] = p; }
    }
  }
#pragma unroll
  for (int off = 1; off < 64; off <<= 1) {
    s0 += __shfl_xor(s0, off);
    s1 += __shfl_xor(s1, off);
  }
  if (lane == 0) { sredA[0][wv] = s0; sredA[1][wv] = s1; }
  __syncthreads();
  s0 = sredA[0][0] + sredA[0][1] + sredA[0][2] + sredA[0][3];
  s1 = sredA[1][0] + sredA[1][1] + sredA[1][2] + sredA[1][3];
  const float inv0 = 2.0f / s0;   // dropout 1/(1-p)=2 folded in
  const float inv1 = 2.0f / s1;
  const int c0 = min(cnt[0], MAXS), c1 = min(cnt[1], MAXS);

  // phase 3: lazy dropout, only on survivors
  for (int idx = t; idx < c0; idx += 256) {
    const uint32_t v = ((uint32_t)b << 22) | ((uint32_t)i << 11) | (uint32_t)survJ[0][idx];
    survP[0][idx] = keep_bit(v) ? survP[0][idx] * inv0 : 0.f;
  }
  for (int idx = t; idx < c1; idx += 256) {
    const uint32_t v = ((uint32_t)b2 << 22) | ((uint32_t)i << 11) | (uint32_t)survJ[1][idx];
    survP[1][idx] = keep_bit(v) ? survP[1][idx] * inv1 : 0.f;
  }
  __syncthreads();

  // phase 4: sparse PV over survivor list
  float acc0 = 0.f, acc1 = 0.f;
  for (int idx = wv; idx < c0; idx += 4) {
    const float c = survP[0][idx];
    if (c != 0.f)
      acc0 += c * Wh[((size_t)(b * NN + survJ[0][idx])) * FOUT + lane];
  }
  for (int idx = wv; idx < c1; idx += 4) {
    const float c = survP[1][idx];
    if (c != 0.f)
      acc1 += c * Wh[((size_t)(b2 * NN + survJ[1][idx])) * FOUT + lane];
  }
  accL[0][wv][lane] = acc0;
  accL[1][wv][lane] = acc1;
  __syncthreads();
  if (t < 128) {
    const int bb = t >> 6, f = t & 63;
    const float r = accL[bb][0][f] + accL[bb][1][f] + accL[bb][2][f] + accL[bb][3][f];
    const int bo = (bb == 0) ? b : b2;
    out[((size_t)bo * NN + i) * FOUT + f] = r;
  }
}

extern "C" void kernel_launch(void* const* d_in, const int* in_sizes, int n_in,
                              void* d_out, int out_size, void* d_ws, size_t ws_size,
                              hipStream_t stream) {
  const float* h   = (const float*)d_in[0];
  const int*   adj = (const int*)d_in[1];
  const float* W   = (const float*)d_in[2];
  const float* a   = (const float*)d_in[3];
  float* out = (float*)d_out;
  float* ws  = (float*)d_ws;

  float* Wh  = ws;                                 // 16384*64 floats
  float* Wh1 = ws + (size_t)NB * NN * FOUT;        // 16384
  float* Wh2 = Wh1 + NB * NN;                      // 16384

  wh_kernel<<<dim3((NB * NN) / 4), dim3(256), 0, stream>>>(h, W, a, Wh, Wh1, Wh2);
  attn_kernel<<<dim3((NB / 2) * NN), dim3(256), 0, stream>>>(adj, Wh, Wh1, Wh2, out);
}

// Round 5
// 51.162 us; speedup vs baseline: 3.4017x; 1.1193x over previous
//
#include <hip/hip_runtime.h>
#include <stdint.h>

#define NB   8
#define NN   2048
#define FIN  128
#define FOUT 64
#define MAXS 512

__device__ __forceinline__ uint32_t rotl32(uint32_t x, uint32_t r) {
  return (x << r) | (x >> (32u - r));
}

// JAX threefry2x32 with key = (0, 42)
__device__ __forceinline__ void threefry_0_42(uint32_t x0, uint32_t x1,
                                              uint32_t& o0, uint32_t& o1) {
  const uint32_t k0 = 0u, k1 = 42u;
  const uint32_t k2 = 0x1BD11BDAu ^ k0 ^ k1;
  x0 += k0; x1 += k1;
#define TFR(r) { x0 += x1; x1 = rotl32(x1, r); x1 ^= x0; }
  TFR(13u) TFR(15u) TFR(26u) TFR(6u)   x0 += k1; x1 += k2 + 1u;
  TFR(17u) TFR(29u) TFR(16u) TFR(24u)  x0 += k2; x1 += k0 + 2u;
  TFR(13u) TFR(15u) TFR(26u) TFR(6u)   x0 += k0; x1 += k1 + 3u;
  TFR(17u) TFR(29u) TFR(16u) TFR(24u)  x0 += k1; x1 += k2 + 4u;
  TFR(13u) TFR(15u) TFR(26u) TFR(6u)   x0 += k2; x1 += k0 + 5u;
#undef TFR
  o0 = x0; o1 = x1;
}

// Partitionable threefry: bits = o0^o1 of threefry(key, 0, v); keep iff bit31==0.
__device__ __forceinline__ bool keep_bit(uint32_t v) {
  uint32_t o0, o1;
  threefry_0_42(0u, v, o0, o1);
  return !((o0 ^ o1) >> 31);
}

// Kernel A: Wh = h @ W, Wh1 = Wh@a[:64], Wh2 = Wh@a[64:]
// 4 rows/wave, scalar accumulators (W LDS read amortized x4, no spill risk).
__global__ __launch_bounds__(256) void wh_kernel(
    const float* __restrict__ h, const float* __restrict__ W,
    const float* __restrict__ a, float* __restrict__ Wh,
    float* __restrict__ Wh1, float* __restrict__ Wh2) {
  __shared__ __align__(16) float wLds[FIN * FOUT];   // 32 KB
  __shared__ __align__(16) float hLds[16][FIN];      // 8 KB
  const int t = threadIdx.x;
  const int wv = t >> 6, lane = t & 63;
  const int rbase = blockIdx.x * 16;
  {
    const float4* W4 = reinterpret_cast<const float4*>(W);
    float4* wL4 = reinterpret_cast<float4*>(wLds);
    for (int idx = t; idx < FIN * FOUT / 4; idx += 256) wL4[idx] = W4[idx];
    const float4* h4 = reinterpret_cast<const float4*>(h + (size_t)rbase * FIN);
    float4* hL4 = reinterpret_cast<float4*>(&hLds[0][0]);
    for (int idx = t; idx < 16 * FIN / 4; idx += 256) hL4[idx] = h4[idx];
  }
  __syncthreads();
  const int r0 = wv * 4;
  float acc0 = 0.f, acc1 = 0.f, acc2 = 0.f, acc3 = 0.f;
#pragma unroll 4
  for (int k = 0; k < FIN; ++k) {
    const float w = wLds[k * FOUT + lane];   // lanes consecutive: 2-way, free
    acc0 += hLds[r0 + 0][k] * w;             // broadcasts
    acc1 += hLds[r0 + 1][k] * w;
    acc2 += hLds[r0 + 2][k] * w;
    acc3 += hLds[r0 + 3][k] * w;
  }
  const float a1 = a[lane], a2 = a[FOUT + lane];
  float accs[4] = {acc0, acc1, acc2, acc3};
#pragma unroll
  for (int r = 0; r < 4; ++r) {
    const int row = rbase + r0 + r;
    Wh[(size_t)row * FOUT + lane] = accs[r];
    float x1 = accs[r] * a1, x2 = accs[r] * a2;
#pragma unroll
    for (int off = 32; off >= 1; off >>= 1) {
      x1 += __shfl_xor(x1, off);
      x2 += __shfl_xor(x2, off);
    }
    if (lane == 0) { Wh1[row] = x1; Wh2[row] = x2; }
  }
}

// Kernel B: per block: batch pair (b, b+4), row i.
// phase 1: ww = adj ? Wh2 : -1e30 -> regs; reduce mW (max connected Wh2).
//   monotonicity: e = LR(wh1+Wh2) is monotone in Wh2, gap_e >= 0.2*gap_w,
//   so Wh2 < mW-116 => p < 1e-10: skip. row e-max = LR(wh1+mW).
// phase 2: slow path (LR+exp) only where ww > mW-116 (~120/2048); sum s;
//          survivors (p>1e-10) compacted into LDS.
// phase 3: threefry ONLY on compacted survivors (~2-5 per row).
// phase 4: sparse PV over survivor list.
__global__ __launch_bounds__(256) void attn_kernel(
    const int* __restrict__ adj, const float* __restrict__ Wh,
    const float* __restrict__ Wh1, const float* __restrict__ Wh2,
    float* __restrict__ out) {
  __shared__ float redA[2][4];
  __shared__ int cnt[2];
  __shared__ int   survJ[2][MAXS];   // 4 KB
  __shared__ float survP[2][MAXS];   // 4 KB
  __shared__ float accL[2][4][FOUT]; // 2 KB

  const int i = blockIdx.x & (NN - 1);
  const int b = blockIdx.x >> 11;                 // 0..3
  const int b2 = b + 4;
  const int t = threadIdx.x;
  const int wv = t >> 6, lane = t & 63;

  const float wh1_0 = Wh1[b * NN + i];
  const float wh1_1 = Wh1[b2 * NN + i];
  const size_t adjBase0 = ((size_t)(b * NN) + i) * NN;
  const size_t adjBase1 = ((size_t)(b2 * NN) + i) * NN;
  const int j0 = t * 8;

  float ww0[8], ww1[8];
  float mW0 = -3.0e38f, mW1 = -3.0e38f;
  {
    const int4   a0a = *reinterpret_cast<const int4*>(adj + adjBase0 + j0);
    const int4   a0b = *reinterpret_cast<const int4*>(adj + adjBase0 + j0 + 4);
    const int4   a1a = *reinterpret_cast<const int4*>(adj + adjBase1 + j0);
    const int4   a1b = *reinterpret_cast<const int4*>(adj + adjBase1 + j0 + 4);
    const float4 w0a = *reinterpret_cast<const float4*>(Wh2 + (size_t)b * NN + j0);
    const float4 w0b = *reinterpret_cast<const float4*>(Wh2 + (size_t)b * NN + j0 + 4);
    const float4 w1a = *reinterpret_cast<const float4*>(Wh2 + (size_t)b2 * NN + j0);
    const float4 w1b = *reinterpret_cast<const float4*>(Wh2 + (size_t)b2 * NN + j0 + 4);
    const int aa0[8] = {a0a.x, a0a.y, a0a.z, a0a.w, a0b.x, a0b.y, a0b.z, a0b.w};
    const int aa1[8] = {a1a.x, a1a.y, a1a.z, a1a.w, a1b.x, a1b.y, a1b.z, a1b.w};
    const float vv0[8] = {w0a.x, w0a.y, w0a.z, w0a.w, w0b.x, w0b.y, w0b.z, w0b.w};
    const float vv1[8] = {w1a.x, w1a.y, w1a.z, w1a.w, w1b.x, w1b.y, w1b.z, w1b.w};
#pragma unroll
    for (int e = 0; e < 8; ++e) {
      ww0[e] = (aa0[e] > 0) ? vv0[e] : -1.0e30f;
      mW0 = fmaxf(mW0, ww0[e]);
      ww1[e] = (aa1[e] > 0) ? vv1[e] : -1.0e30f;
      mW1 = fmaxf(mW1, ww1[e]);
    }
  }
#pragma unroll
  for (int off = 1; off < 64; off <<= 1) {
    mW0 = fmaxf(mW0, __shfl_xor(mW0, off));
    mW1 = fmaxf(mW1, __shfl_xor(mW1, off));
  }
  if (lane == 0) { redA[0][wv] = mW0; redA[1][wv] = mW1; }
  if (t < 2) cnt[t] = 0;
  __syncthreads();
  mW0 = fmaxf(fmaxf(redA[0][0], redA[0][1]), fmaxf(redA[0][2], redA[0][3]));
  mW1 = fmaxf(fmaxf(redA[1][0], redA[1][1]), fmaxf(redA[1][2], redA[1][3]));

  const float me0_arg = wh1_0 + mW0;
  const float me1_arg = wh1_1 + mW1;
  const float me0 = (me0_arg < 0.f) ? 0.2f * me0_arg : me0_arg;  // row max of e
  const float me1 = (me1_arg < 0.f) ? 0.2f * me1_arg : me1_arg;
  const float thr0 = mW0 - 116.f;
  const float thr1 = mW1 - 116.f;

  float s0 = 0.f, s1 = 0.f;
#pragma unroll
  for (int k = 0; k < 8; ++k) {
    if (ww0[k] > thr0) {
      float x = wh1_0 + ww0[k];
      x = (x < 0.f) ? 0.2f * x : x;
      const float p = __expf(x - me0);
      s0 += p;
      if (p > 1e-10f) {
        const int idx = atomicAdd(&cnt[0], 1);
        if (idx < MAXS) { survJ[0][idx] = j0 + k; survP[0][idx] = p; }
      }
    }
    if (ww1[k] > thr1) {
      float y = wh1_1 + ww1[k];
      y = (y < 0.f) ? 0.2f * y : y;
      const float p = __expf(y - me1);
      s1 += p;
      if (p > 1e-10f) {
        const int idx = atomicAdd(&cnt[1], 1);
        if (idx < MAXS) { survJ[1][idx] = j0 + k; survP[1][idx] = p; }
      }
    }
  }
#pragma unroll
  for (int off = 1; off < 64; off <<= 1) {
    s0 += __shfl_xor(s0, off);
    s1 += __shfl_xor(s1, off);
  }
  if (lane == 0) { redA[0][wv] = s0; redA[1][wv] = s1; }
  __syncthreads();
  s0 = redA[0][0] + redA[0][1] + redA[0][2] + redA[0][3];
  s1 = redA[1][0] + redA[1][1] + redA[1][2] + redA[1][3];
  const float inv0 = 2.0f / s0;   // dropout 1/(1-p)=2 folded in
  const float inv1 = 2.0f / s1;
  const int c0 = min(cnt[0], MAXS), c1 = min(cnt[1], MAXS);

  // phase 3: lazy dropout, only on survivors
  for (int idx = t; idx < c0; idx += 256) {
    const uint32_t v = ((uint32_t)b << 22) | ((uint32_t)i << 11) | (uint32_t)survJ[0][idx];
    survP[0][idx] = keep_bit(v) ? survP[0][idx] * inv0 : 0.f;
  }
  for (int idx = t; idx < c1; idx += 256) {
    const uint32_t v = ((uint32_t)b2 << 22) | ((uint32_t)i << 11) | (uint32_t)survJ[1][idx];
    survP[1][idx] = keep_bit(v) ? survP[1][idx] * inv1 : 0.f;
  }
  __syncthreads();

  // phase 4: sparse PV over survivor list
  float acc0 = 0.f, acc1 = 0.f;
  for (int idx = wv; idx < c0; idx += 4) {
    const float c = survP[0][idx];
    if (c != 0.f)
      acc0 += c * Wh[((size_t)(b * NN + survJ[0][idx])) * FOUT + lane];
  }
  for (int idx = wv; idx < c1; idx += 4) {
    const float c = survP[1][idx];
    if (c != 0.f)
      acc1 += c * Wh[((size_t)(b2 * NN + survJ[1][idx])) * FOUT + lane];
  }
  accL[0][wv][lane] = acc0;
  accL[1][wv][lane] = acc1;
  __syncthreads();
  if (t < 128) {
    const int bb = t >> 6, f = t & 63;
    const float r = accL[bb][0][f] + accL[bb][1][f] + accL[bb][2][f] + accL[bb][3][f];
    const int bo = (bb == 0) ? b : b2;
    out[((size_t)bo * NN + i) * FOUT + f] = r;
  }
}

extern "C" void kernel_launch(void* const* d_in, const int* in_sizes, int n_in,
                              void* d_out, int out_size, void* d_ws, size_t ws_size,
                              hipStream_t stream) {
  const float* h   = (const float*)d_in[0];
  const int*   adj = (const int*)d_in[1];
  const float* W   = (const float*)d_in[2];
  const float* a   = (const float*)d_in[3];
  float* out = (float*)d_out;
  float* ws  = (float*)d_ws;

  float* Wh  = ws;                                 // 16384*64 floats
  float* Wh1 = ws + (size_t)NB * NN * FOUT;        // 16384
  float* Wh2 = Wh1 + NB * NN;                      // 16384

  wh_kernel<<<dim3((NB * NN) / 16), dim3(256), 0, stream>>>(h, W, a, Wh, Wh1, Wh2);
  attn_kernel<<<dim3((NB / 2) * NN), dim3(256), 0, stream>>>(adj, Wh, Wh1, Wh2, out);
}